// Round 12
// baseline (453.886 us; speedup 1.0000x reference)
//
#include <hip/hip_runtime.h>
#include <hip/hip_bf16.h>
#include <stdint.h>
#include <math.h>

// Problem constants
#define NB 4
#define NT 2048
#define NC 2048
#define NH 16
#define HD 128
#define BT (NB*NT)   // 8192

typedef __attribute__((ext_vector_type(8))) short s16x8;
typedef __attribute__((ext_vector_type(4))) short s16x4;
typedef __attribute__((ext_vector_type(4))) float f32x4;

typedef __attribute__((address_space(1))) void as1_void;
typedef __attribute__((address_space(3))) void as3_void;

#define CFENCE asm volatile("" ::: "memory")

static __device__ __forceinline__ unsigned short f2bf(float f) {
  union { float f; uint32_t u; } v; v.f = f;
  return (unsigned short)((v.u + 0x7fffu + ((v.u >> 16) & 1u)) >> 16);
}
static __device__ __forceinline__ float bf2f(unsigned short u) {
  union { uint32_t u; float f; } v; v.u = ((uint32_t)u) << 16;
  return v.f;
}
static __device__ __forceinline__ void async16(unsigned short* lds, const unsigned short* g) {
  __builtin_amdgcn_global_load_lds((as1_void*)g, (as3_void*)lds, 16, 0, 0);
}
static __device__ __forceinline__ uint32_t lds_off(void* p) {
  return (uint32_t)(size_t)(as3_void*)p;
}

// ---------------- fp32 -> bf16 convert (vectorized, 8 elems/thread) ----------------
__global__ void k_convert_bf16(const float* __restrict__ in, unsigned short* __restrict__ out, int n8) {
  int i = blockIdx.x * blockDim.x + threadIdx.x;
  if (i >= n8) return;
  const float4* p = (const float4*)in + (size_t)i * 2;
  float4 a = p[0], b = p[1];
  union { unsigned short s[8]; uint4 u; } o;
  o.s[0] = f2bf(a.x); o.s[1] = f2bf(a.y); o.s[2] = f2bf(a.z); o.s[3] = f2bf(a.w);
  o.s[4] = f2bf(b.x); o.s[5] = f2bf(b.y); o.s[6] = f2bf(b.z); o.s[7] = f2bf(b.w);
  ((uint4*)out)[i] = o.u;
}

// ---------------- transpose + convert: W [K][N] fp32 -> WT [N][K] bf16 ----------------
__global__ void k_transpose_bf16(const float* __restrict__ W, unsigned short* __restrict__ WT, int K, int N) {
  __shared__ unsigned short tile[64][65];
  const int k0 = blockIdx.y * 64, n0 = blockIdx.x * 64;
  const int t = threadIdx.x;
  const int jj = t & 63, base_i = t >> 6;
  #pragma unroll
  for (int p = 0; p < 16; ++p) {
    int i = p * 4 + base_i;
    tile[i][jj] = f2bf(W[(size_t)(k0 + i) * N + n0 + jj]);
  }
  __syncthreads();
  #pragma unroll
  for (int p = 0; p < 16; ++p) {
    int j = p * 4 + base_i;
    WT[(size_t)(n0 + j) * K + k0 + jj] = tile[jj][j];
  }
}

// ---------------- RoPE in-place on Q,K [BH][T][D]; fold scale*log2e into Q ----------------
// Vectorized (G13): thread handles 8 d-pairs; short8 loads/stores.
__global__ void k_rope(unsigned short* __restrict__ Q, unsigned short* __restrict__ Kb) {
  int idx = blockIdx.x * 256 + threadIdx.x;  // over BH*T*8
  int g = idx & 7;                            // d-octet: d = g*8+e
  int tpos = (idx >> 3) & (NT - 1);
  int bh = idx >> 14;
  size_t o = ((size_t)bh * NT + tpos) * HD + g * 8;
  s16x8 qlo = *(const s16x8*)(Q + o),  qhi = *(const s16x8*)(Q + o + 64);
  s16x8 klo = *(const s16x8*)(Kb + o), khi = *(const s16x8*)(Kb + o + 64);
  s16x8 oql, oqh, okl, okh;
  const float qs = 0.08838834764831845f * 1.4426950408889634f;  // (1/sqrt(128))*log2e
  #pragma unroll
  for (int e = 0; e < 8; ++e) {
    const int d = g * 8 + e;
    float invf = exp2f(-(float)d * 0.2076205059304602f);  // log2(10000)/64
    float ang = (float)tpos * invf;
    float s, c;
    __sincosf(ang, &s, &c);
    float q1 = bf2f((unsigned short)qlo[e]), q2 = bf2f((unsigned short)qhi[e]);
    float k1 = bf2f((unsigned short)klo[e]), k2 = bf2f((unsigned short)khi[e]);
    oql[e] = (short)f2bf((q1 * c - q2 * s) * qs);
    oqh[e] = (short)f2bf((q2 * c + q1 * s) * qs);
    okl[e] = (short)f2bf(k1 * c - k2 * s);
    okh[e] = (short)f2bf(k2 * c + k1 * s);
  }
  *(s16x8*)(Q + o)       = oql;
  *(s16x8*)(Q + o + 64)  = oqh;
  *(s16x8*)(Kb + o)      = okl;
  *(s16x8*)(Kb + o + 64) = okh;
}

// ---------------- GEMM 256x128 block, ring-3 K-slice pipeline (T4 counted vmcnt) ----
// 4 waves (2Mx2N), wave tile 128x64. Units = 32-deep K-slices: A 256x32 (16KB) +
// B 128x32 (8KB) = 24KB/slot, 3 slots = 72KB -> 2 blocks/CU. Iter u stages unit
// u+2 into slot (u+2)%3 — freed by unit u-1 a barrier ago => race-free regardless
// of landing time. Ledger: 6 load-insts/unit/wave; vmcnt(6) at iter end drains
// exactly unit u+1, leaves u+2's 6 in flight ACROSS the barrier (never drains to 0).
// LDS unit layout [lines of 2 rows][8 slots]: slot = ((row&1)<<2 | kchunk) ^ (line&7)
// — measured-0-conflict scheme; linear gload_lds dest, pre-swizzled global source.
// __launch_bounds__(256,2) MANDATORY (r3/r8: min-waves 3+ spills the 128-reg acc).
// MODE 0: scatter bf16 into Q/K/V [B][H][T][D]. MODE 1: fp32 row-major out.
template<int MODE>
__global__ __launch_bounds__(256, 2)
void k_gemm_ring(const unsigned short* __restrict__ A,
                 const unsigned short* __restrict__ Bt,
                 const float* __restrict__ bias,
                 float* __restrict__ OutF,
                 unsigned short* __restrict__ Qd,
                 unsigned short* __restrict__ Kd,
                 unsigned short* __restrict__ Vd,
                 int M, int N, int K)
{
  __shared__ __align__(16) unsigned short As[3][8192];
  __shared__ __align__(16) unsigned short Bs[3][4096];
  const int t = threadIdx.x;
  const int l = t & 63;
  const int wv = t >> 6;
  const int wm = wv >> 1, wn = wv & 1;     // 2 x 2 wave grid; wave tile 128x64
  const int bm = blockIdx.y * 256, bn = blockIdx.x * 128;
  const int lr = l & 15, lg = l >> 4;

  f32x4 acc[8][4];
  #pragma unroll
  for (int i = 0; i < 8; ++i)
    #pragma unroll
    for (int j = 0; j < 4; ++j)
      acc[i][j] = f32x4{0.f, 0.f, 0.f, 0.f};

  // pre-swizzled stage decode: chunk Cc=j*256+t -> (row, kchunk) for loads j=0..3
  int arow[4], akc[4];
  #pragma unroll
  for (int j = 0; j < 4; ++j) {
    const int Cc = j * 256 + t;
    const int lq = Cc >> 3;
    const int vl = (Cc & 7) ^ (lq & 7);
    arow[j] = 2 * lq + (vl >> 2);
    akc[j] = vl & 3;
  }

  auto stage = [&](int s, int k0) {
    #pragma unroll
    for (int j = 0; j < 4; ++j)
      async16(&As[s][(j * 256 + (t & 192)) * 8], &A[(size_t)(bm + arow[j]) * K + k0 + akc[j] * 8]);
    #pragma unroll
    for (int j = 0; j < 2; ++j)
      async16(&Bs[s][(j * 256 + (t & 192)) * 8], &Bt[(size_t)(bn + arow[j]) * K + k0 + akc[j] * 8]);
  };
  auto compute = [&](int s) {
    s16x8 af[8], bfr[4];
    #pragma unroll
    for (int mi = 0; mi < 8; ++mi) {
      const int row = wm * 128 + mi * 16 + lr;
      const int lq = row >> 1;
      const int sl = (((row & 1) << 2) | lg) ^ (lq & 7);
      af[mi] = *(const s16x8*)&As[s][lq * 64 + sl * 8];
    }
    #pragma unroll
    for (int ni = 0; ni < 4; ++ni) {
      const int row = wn * 64 + ni * 16 + lr;
      const int lq = row >> 1;
      const int sl = (((row & 1) << 2) | lg) ^ (lq & 7);
      bfr[ni] = *(const s16x8*)&Bs[s][lq * 64 + sl * 8];
    }
    __builtin_amdgcn_s_setprio(1);
    #pragma unroll
    for (int mi = 0; mi < 8; ++mi)
      #pragma unroll
      for (int ni = 0; ni < 4; ++ni)
        acc[mi][ni] = __builtin_amdgcn_mfma_f32_16x16x32_bf16(af[mi], bfr[ni], acc[mi][ni], 0, 0, 0);
    __builtin_amdgcn_s_setprio(0);
  };

  // prologue: stage units 0,1 -> slots 0,1; wait unit 0 (leave unit 1 in flight)
  stage(0, 0); stage(1, 32);
  asm volatile("s_waitcnt vmcnt(6)" ::: "memory");
  CFENCE; __builtin_amdgcn_s_barrier(); CFENCE;

  const int nU = K >> 5;
  int sr = 0;
  #pragma unroll 1
  for (int u = 0; u < nU; ++u) {
    int s2 = sr + 2; if (s2 >= 3) s2 -= 3;
    const int kn = (u + 2 < nU) ? ((u + 2) << 5) : 0;  // clamped dummy keeps ledger uniform
    stage(s2, kn);
    compute(sr);
    asm volatile("s_waitcnt vmcnt(6)" ::: "memory");   // drains unit u+1; u+2 stays in flight
    CFENCE; __builtin_amdgcn_s_barrier(); CFENCE;
    sr = (sr + 1 == 3) ? 0 : sr + 1;
  }

  // epilogue; C/D layout: col = lane&15, row = (lane>>4)*4 + reg  [m89-verified]
  #pragma unroll
  for (int mi = 0; mi < 8; ++mi) {
    #pragma unroll
    for (int ni = 0; ni < 4; ++ni) {
      const int col = bn + wn * 64 + ni * 16 + lr;
      const float bv = bias[col];
      #pragma unroll
      for (int r = 0; r < 4; ++r) {
        const int row = bm + wm * 128 + mi * 16 + lg * 4 + r;
        const float v = acc[mi][ni][r] + bv;
        if (MODE == 1) {
          OutF[(size_t)row * N + col] = v;
        } else {
          const int which = col >> 11;         // 0=q 1=k 2=v (uniform per block: 2048%128==0)
          const int cc = col & 2047;
          const int h = cc >> 7, d = cc & 127;
          const int b = row >> 11, tp = row & 2047;
          unsigned short* dst = (which == 0) ? Qd : (which == 1 ? Kd : Vd);
          dst[(((size_t)(b * NH + h)) * NT + tp) * HD + d] = f2bf(v);
        }
      }
    }
  }
}

// ---------------- flash attention: 4 waves x 32 q-rows (2 frags), KV tile 64, dbuf ----------------
// Each lane owns TWO q-rows; K-frag LDS reads, V tr-reads, and KV staging SHARED
// across both fragments. Block = 128 q-rows; grid (bh 64, pair 8); pair balance
// (i, 15-i) -> 34 kv-iters const; same-head blocks on one XCD.
// swapped S^T = mfma(K, Q); T13 defer-max; cvt_pk P-pack; packed 8B output stores.
// Final tile skipped by waves 0,1 (fully causal-masked there — exact-zero contribution).
__global__ __launch_bounds__(256, 2)
void k_attn(const unsigned short* __restrict__ Q,
            const unsigned short* __restrict__ Kg,
            const unsigned short* __restrict__ Vg,
            unsigned short* __restrict__ Yatt)   // att [BT][NC] bf16
{
  __shared__ __align__(16) unsigned short Kl[2][64 * 128];  // [key][d], 16B-chunk-swizzled
  __shared__ __align__(16) unsigned short Vl[2][64 * 128];  // subtiled [key/4][d/16][4][16]
  const int bh = blockIdx.x;          // 0..63
  const int pair = blockIdx.y;        // 0..7
  const int b = bh >> 4, h = bh & 15;
  const int t = threadIdx.x, l = t & 63, wv = t >> 6;
  const int lr = l & 15, lg = l >> 4;
  const size_t hoff = (size_t)bh * NT * HD;
  const unsigned short* Qh = Q + hoff;
  const unsigned short* Kh = Kg + hoff;
  const unsigned short* Vh = Vg + hoff;
  const uint32_t vbase0 = lds_off(&Vl[0][0]);

  auto stageKV = [&](int buf, int kv0) {
    #pragma unroll
    for (int i = 0; i < 4; ++i) {
      const int Cc = i * 256 + t;
      {  // K tile: row-major [64][128], 16B chunks swizzled with (row&7)
        const int krow = Cc >> 4;
        const int kc = (Cc & 15) ^ (krow & 7);
        async16(&Kl[buf][(i * 256 + (t & 192)) * 8], &Kh[(size_t)(kv0 + krow) * HD + kc * 8]);
      }
      {  // V tile: subtile S = kq*8+dq holds [4 keys][16 d] row-major
        const int S = Cc >> 3, c8 = Cc & 7;
        const int kq = S >> 3, dq = S & 7;
        const int vk = kq * 4 + (c8 >> 1), vd = dq * 16 + (c8 & 1) * 8;
        async16(&Vl[buf][(i * 256 + (t & 192)) * 8], &Vh[(size_t)(kv0 + vk) * HD + vd]);
      }
    }
  };

  #pragma unroll 1
  for (int rep = 0; rep < 2; ++rep) {
    const int qb16 = rep ? (15 - pair) : pair;   // q-tile of 128 rows
    const int q0w = qb16 * 128 + wv * 32;        // wave's 32-row strip
    const int qrowA = q0w + lr, qrowB = q0w + 16 + lr;

    __syncthreads();  // protect LDS reuse across reps

    s16x8 qfA[4], qfB[4];
    #pragma unroll
    for (int m = 0; m < 4; ++m) {
      qfA[m] = *(const s16x8*)(Qh + (size_t)qrowA * HD + m * 32 + lg * 8);
      qfB[m] = *(const s16x8*)(Qh + (size_t)qrowB * HD + m * 32 + lg * 8);
    }

    f32x4 ytA[8], ytB[8];
    #pragma unroll
    for (int n = 0; n < 8; ++n) { ytA[n] = f32x4{0.f,0.f,0.f,0.f}; ytB[n] = f32x4{0.f,0.f,0.f,0.f}; }
    float mrunA = -1e30f, lrunA = 0.f, mrunB = -1e30f, lrunB = 0.f;

    auto computeTile = [&](int buf, int kv0) {
      // S^T tiles for both q-frags; K frags shared
      f32x4 stA[4], stB[4];
      __builtin_amdgcn_s_setprio(1);
      #pragma unroll
      for (int kt = 0; kt < 4; ++kt) {
        f32x4 a = f32x4{0.f,0.f,0.f,0.f}, bq = f32x4{0.f,0.f,0.f,0.f};
        const int krow = kt * 16 + lr;
        #pragma unroll
        for (int m = 0; m < 4; ++m) {
          const int ch = (m * 4 + lg) ^ (krow & 7);
          s16x8 kf = *(const s16x8*)&Kl[buf][krow * 128 + ch * 8];
          a  = __builtin_amdgcn_mfma_f32_16x16x32_bf16(kf, qfA[m], a, 0, 0, 0);
          bq = __builtin_amdgcn_mfma_f32_16x16x32_bf16(kf, qfB[m], bq, 0, 0, 0);
        }
        stA[kt] = a; stB[kt] = bq;
      }
      __builtin_amdgcn_s_setprio(0);

      // causal mask near diagonal (per frag)
      if (kv0 + 63 > q0w) {
        #pragma unroll
        for (int kt = 0; kt < 4; ++kt)
          #pragma unroll
          for (int r = 0; r < 4; ++r) {
            const int key = kv0 + kt * 16 + lg * 4 + r;
            if (key > qrowA) stA[kt][r] = -3.0e38f;
            if (key > qrowB) stB[kt][r] = -3.0e38f;
          }
      }

      // online softmax x2 (T13 defer-max)
      float tmA = -3.0e38f, tmB = -3.0e38f;
      #pragma unroll
      for (int kt = 0; kt < 4; ++kt)
        #pragma unroll
        for (int r = 0; r < 4; ++r) { tmA = fmaxf(tmA, stA[kt][r]); tmB = fmaxf(tmB, stB[kt][r]); }
      tmA = fmaxf(tmA, __shfl_xor(tmA, 16)); tmA = fmaxf(tmA, __shfl_xor(tmA, 32));
      tmB = fmaxf(tmB, __shfl_xor(tmB, 16)); tmB = fmaxf(tmB, __shfl_xor(tmB, 32));
      if (!__all((tmA - mrunA <= 8.0f) && (tmB - mrunB <= 8.0f))) {
        const float mnA = fmaxf(mrunA, tmA), mnB = fmaxf(mrunB, tmB);
        const float fsA = exp2f(mrunA - mnA), fsB = exp2f(mrunB - mnB);
        mrunA = mnA; mrunB = mnB;
        lrunA *= fsA; lrunB *= fsB;
        #pragma unroll
        for (int n = 0; n < 8; ++n)
          #pragma unroll
          for (int r = 0; r < 4; ++r) { ytA[n][r] *= fsA; ytB[n][r] *= fsB; }
      }

      float pvA[16], pvB[16];
      float psA = 0.f, psB = 0.f;
      #pragma unroll
      for (int kt = 0; kt < 4; ++kt)
        #pragma unroll
        for (int r = 0; r < 4; ++r) {
          const float pa = exp2f(stA[kt][r] - mrunA);
          const float pb = exp2f(stB[kt][r] - mrunB);
          psA += pa; psB += pb;
          pvA[kt * 4 + r] = pa; pvB[kt * 4 + r] = pb;
        }
      lrunA += psA; lrunB += psB;

      // pack P^T frags via v_cvt_pk_bf16_f32
      union { uint32_t w[4]; s16x8 v; } puA[2], puB[2];
      #pragma unroll
      for (int gk = 0; gk < 2; ++gk)
        #pragma unroll
        for (int w = 0; w < 4; ++w) {
          const int i0 = (gk * 2 + (w >> 1)) * 4 + (w & 1) * 2;
          asm("v_cvt_pk_bf16_f32 %0, %1, %2" : "=v"(puA[gk].w[w]) : "v"(pvA[i0]), "v"(pvA[i0 + 1]));
          asm("v_cvt_pk_bf16_f32 %0, %1, %2" : "=v"(puB[gk].w[w]) : "v"(pvB[i0]), "v"(pvB[i0 + 1]));
        }

      // PV: V^T frags shared across both q-frags
      const uint32_t vb = vbase0 + (uint32_t)buf * 16384;
      #pragma unroll
      for (int gk = 0; gk < 2; ++gk) {
        s16x4 va[8], vb2[8];
        #pragma unroll
        for (int n = 0; n < 8; ++n) {
          const uint32_t a0 = vb + ((uint32_t)((gk * 8 + lg) * 8 + n)) * 128 + (uint32_t)lr * 8;
          asm volatile("ds_read_b64_tr_b16 %0, %1" : "=v"(va[n])  : "v"(a0));
          asm volatile("ds_read_b64_tr_b16 %0, %1" : "=v"(vb2[n]) : "v"(a0 + 4096));
        }
        asm volatile("s_waitcnt lgkmcnt(0)" ::: "memory");
        __builtin_amdgcn_sched_barrier(0);
        __builtin_amdgcn_s_setprio(1);
        #pragma unroll
        for (int n = 0; n < 8; ++n) {
          s16x8 vf;
          vf[0] = va[n][0];  vf[1] = va[n][1];  vf[2] = va[n][2];  vf[3] = va[n][3];
          vf[4] = vb2[n][0]; vf[5] = vb2[n][1]; vf[6] = vb2[n][2]; vf[7] = vb2[n][3];
          ytA[n] = __builtin_amdgcn_mfma_f32_16x16x32_bf16(vf, puA[gk].v, ytA[n], 0, 0, 0);
          ytB[n] = __builtin_amdgcn_mfma_f32_16x16x32_bf16(vf, puB[gk].v, ytB[n], 0, 0, 0);
        }
        __builtin_amdgcn_s_setprio(0);
      }
    };

    const int nkv = 2 * qb16 + 2;
    stageKV(0, 0);
    asm volatile("s_waitcnt vmcnt(0)" ::: "memory");
    __syncthreads();
    int buf = 0;
    #pragma unroll 1
    for (int kv = 0; kv < nkv - 1; ++kv) {
      stageKV(buf ^ 1, (kv + 1) * 64);      // issue next tile's loads first
      computeTile(buf, kv * 64);            // overlap compute with loads
      asm volatile("s_waitcnt vmcnt(0)" ::: "memory");
      __builtin_amdgcn_s_barrier();
      buf ^= 1;
    }
    if ((nkv - 1) * 64 <= q0w + 31)         // waves 0,1: final tile fully masked -> skip
      computeTile(buf, (nkv - 1) * 64);

    // finalize both frags: reduce l, scale, packed 8B stores
    lrunA += __shfl_xor(lrunA, 16); lrunA += __shfl_xor(lrunA, 32);
    lrunB += __shfl_xor(lrunB, 16); lrunB += __shfl_xor(lrunB, 32);
    const float invA = 1.f / lrunA, invB = 1.f / lrunB;
    unsigned short* yrowA = Yatt + (size_t)(b * NT + qrowA) * NC + h * HD;
    unsigned short* yrowB = Yatt + (size_t)(b * NT + qrowB) * NC + h * HD;
    #pragma unroll
    for (int n = 0; n < 8; ++n) {
      uint32_t u0, u1;
      asm("v_cvt_pk_bf16_f32 %0, %1, %2" : "=v"(u0) : "v"(ytA[n][0] * invA), "v"(ytA[n][1] * invA));
      asm("v_cvt_pk_bf16_f32 %0, %1, %2" : "=v"(u1) : "v"(ytA[n][2] * invA), "v"(ytA[n][3] * invA));
      uint2 pk; pk.x = u0; pk.y = u1;
      *(uint2*)(yrowA + n * 16 + lg * 4) = pk;
      asm("v_cvt_pk_bf16_f32 %0, %1, %2" : "=v"(u0) : "v"(ytB[n][0] * invB), "v"(ytB[n][1] * invB));
      asm("v_cvt_pk_bf16_f32 %0, %1, %2" : "=v"(u1) : "v"(ytB[n][2] * invB), "v"(ytB[n][3] * invB));
      pk.x = u0; pk.y = u1;
      *(uint2*)(yrowB + n * 16 + lg * 4) = pk;
    }
  }
}

extern "C" void kernel_launch(void* const* d_in, const int* in_sizes, int n_in,
                              void* d_out, int out_size, void* d_ws, size_t ws_size,
                              hipStream_t stream) {
  (void)in_sizes; (void)n_in; (void)out_size; (void)ws_size;
  const float* x     = (const float*)d_in[0];
  const float* Wqkv  = (const float*)d_in[1];
  const float* bqkv  = (const float*)d_in[2];
  const float* Wproj = (const float*)d_in[3];
  const float* bproj = (const float*)d_in[4];
  float* out = (float*)d_out;
  char* ws = (char*)d_ws;

  // workspace layout (160 MB total)
  unsigned short* xb     = (unsigned short*)(ws);               // 32MB  [BT][NC] bf16
  unsigned short* WqkvT  = (unsigned short*)(ws + 33554432);    // 24MB  [6144][2048]
  unsigned short* WprojT = (unsigned short*)(ws + 58720256);    // 8MB   [2048][2048]
  unsigned short* Qb     = (unsigned short*)(ws + 67108864);    // 32MB  [BH][T][D]
  unsigned short* Kb     = (unsigned short*)(ws + 100663296);   // 32MB
  unsigned short* Vb     = (unsigned short*)(ws + 134217728);   // 32MB
  unsigned short* att    = xb;  // reuse (xb dead after GEMM1)

  k_convert_bf16<<<dim3(8192), dim3(256), 0, stream>>>(x, xb, BT * NC / 8);
  k_transpose_bf16<<<dim3(96, 32), dim3(256), 0, stream>>>(Wqkv, WqkvT, NC, 3 * NC);
  k_transpose_bf16<<<dim3(32, 32), dim3(256), 0, stream>>>(Wproj, WprojT, NC, NC);
  k_gemm_ring<0><<<dim3(48, 32), dim3(256), 0, stream>>>(xb, WqkvT, bqkv, nullptr, Qb, Kb, Vb, BT, 3 * NC, NC);
  k_rope<<<dim3(4096), dim3(256), 0, stream>>>(Qb, Kb);
  k_attn<<<dim3(64, 8), dim3(256), 0, stream>>>(Qb, Kb, Vb, att);
  k_gemm_ring<1><<<dim3(16, 32), dim3(256), 0, stream>>>(att, WprojT, bproj, out, nullptr, nullptr, nullptr, BT, NC, NC);
}

// Round 13
// 408.591 us; speedup vs baseline: 1.1109x; 1.1109x over previous
//
#include <hip/hip_runtime.h>
#include <hip/hip_bf16.h>
#include <stdint.h>
#include <math.h>

// Problem constants
#define NB 4
#define NT 2048
#define NC 2048
#define NH 16
#define HD 128
#define BT (NB*NT)   // 8192

typedef __attribute__((ext_vector_type(8))) short s16x8;
typedef __attribute__((ext_vector_type(4))) short s16x4;
typedef __attribute__((ext_vector_type(4))) float f32x4;

typedef __attribute__((address_space(1))) void as1_void;
typedef __attribute__((address_space(3))) void as3_void;

static __device__ __forceinline__ unsigned short f2bf(float f) {
  union { float f; uint32_t u; } v; v.f = f;
  return (unsigned short)((v.u + 0x7fffu + ((v.u >> 16) & 1u)) >> 16);
}
static __device__ __forceinline__ float bf2f(unsigned short u) {
  union { uint32_t u; float f; } v; v.u = ((uint32_t)u) << 16;
  return v.f;
}
static __device__ __forceinline__ void async16(unsigned short* lds, const unsigned short* g) {
  __builtin_amdgcn_global_load_lds((as1_void*)g, (as3_void*)lds, 16, 0, 0);
}
static __device__ __forceinline__ uint32_t lds_off(void* p) {
  return (uint32_t)(size_t)(as3_void*)p;
}

// ---------------- fp32 -> bf16 convert (vectorized, 8 elems/thread) ----------------
__global__ void k_convert_bf16(const float* __restrict__ in, unsigned short* __restrict__ out, int n8) {
  int i = blockIdx.x * blockDim.x + threadIdx.x;
  if (i >= n8) return;
  const float4* p = (const float4*)in + (size_t)i * 2;
  float4 a = p[0], b = p[1];
  union { unsigned short s[8]; uint4 u; } o;
  o.s[0] = f2bf(a.x); o.s[1] = f2bf(a.y); o.s[2] = f2bf(a.z); o.s[3] = f2bf(a.w);
  o.s[4] = f2bf(b.x); o.s[5] = f2bf(b.y); o.s[6] = f2bf(b.z); o.s[7] = f2bf(b.w);
  ((uint4*)out)[i] = o.u;
}

// ---------------- transpose + convert: W [K][N] fp32 -> WT [N][K] bf16 ----------------
__global__ void k_transpose_bf16(const float* __restrict__ W, unsigned short* __restrict__ WT, int K, int N) {
  __shared__ unsigned short tile[64][65];
  const int k0 = blockIdx.y * 64, n0 = blockIdx.x * 64;
  const int t = threadIdx.x;
  const int jj = t & 63, base_i = t >> 6;
  #pragma unroll
  for (int p = 0; p < 16; ++p) {
    int i = p * 4 + base_i;
    tile[i][jj] = f2bf(W[(size_t)(k0 + i) * N + n0 + jj]);
  }
  __syncthreads();
  #pragma unroll
  for (int p = 0; p < 16; ++p) {
    int j = p * 4 + base_i;
    WT[(size_t)(n0 + j) * K + k0 + jj] = tile[jj][j];
  }
}

// ---------------- RoPE in-place on Q,K [BH][T][D]; fold scale*log2e into Q ----------------
// Vectorized (G13): thread handles 8 d-pairs; short8 loads/stores.
__global__ void k_rope(unsigned short* __restrict__ Q, unsigned short* __restrict__ Kb) {
  int idx = blockIdx.x * 256 + threadIdx.x;  // over BH*T*8
  int g = idx & 7;                            // d-octet: d = g*8+e
  int tpos = (idx >> 3) & (NT - 1);
  int bh = idx >> 14;
  size_t o = ((size_t)bh * NT + tpos) * HD + g * 8;
  s16x8 qlo = *(const s16x8*)(Q + o),  qhi = *(const s16x8*)(Q + o + 64);
  s16x8 klo = *(const s16x8*)(Kb + o), khi = *(const s16x8*)(Kb + o + 64);
  s16x8 oql, oqh, okl, okh;
  const float qs = 0.08838834764831845f * 1.4426950408889634f;  // (1/sqrt(128))*log2e
  #pragma unroll
  for (int e = 0; e < 8; ++e) {
    const int d = g * 8 + e;
    float invf = exp2f(-(float)d * 0.2076205059304602f);  // log2(10000)/64
    float ang = (float)tpos * invf;
    float s, c;
    __sincosf(ang, &s, &c);
    float q1 = bf2f((unsigned short)qlo[e]), q2 = bf2f((unsigned short)qhi[e]);
    float k1 = bf2f((unsigned short)klo[e]), k2 = bf2f((unsigned short)khi[e]);
    oql[e] = (short)f2bf((q1 * c - q2 * s) * qs);
    oqh[e] = (short)f2bf((q2 * c + q1 * s) * qs);
    okl[e] = (short)f2bf(k1 * c - k2 * s);
    okh[e] = (short)f2bf(k2 * c + k1 * s);
  }
  *(s16x8*)(Q + o)       = oql;
  *(s16x8*)(Q + o + 64)  = oqh;
  *(s16x8*)(Kb + o)      = okl;
  *(s16x8*)(Kb + o + 64) = okh;
}

// ---------------- GEMM 256x128 block, BK=64, 256 thr / 4 waves (2Mx2N) ----------------
// FROZEN config (session GEMM optimum): wave tile 128x64, LDS 48 KiB, 2 blocks/CU,
// 2-phase __syncthreads, chunk-XOR swizzle (0 conflicts), natural blockIdx (no XCD
// swizzle — r11: +82% FETCH). __launch_bounds__(256,2) MANDATORY (r3/r8 spills).
// Structural ledger: r5 4-phase, r6 256², r12 ring-3 all regressed (barrier-
// frequency tax / occupancy collapse). Do not re-attempt without the full m201
// template. MODE 0: scatter bf16 Q/K/V. MODE 1: fp32 row-major out.
template<int MODE>
__global__ __launch_bounds__(256, 2)
void k_gemm_bt2(const unsigned short* __restrict__ A,
                const unsigned short* __restrict__ Bt,
                const float* __restrict__ bias,
                float* __restrict__ OutF,
                unsigned short* __restrict__ Qd,
                unsigned short* __restrict__ Kd,
                unsigned short* __restrict__ Vd,
                int M, int N, int K)
{
  __shared__ __align__(16) unsigned short Al[256 * 64];
  __shared__ __align__(16) unsigned short Bl[128 * 64];
  const int t = threadIdx.x;
  const int l = t & 63;
  const int wv = t >> 6;
  const int wm = wv >> 1, wn = wv & 1;     // 2 x 2 wave grid; wave tile 128x64
  const int bm = blockIdx.y * 256, bn = blockIdx.x * 128;
  const int lr = l & 15, lg = l >> 4;

  f32x4 acc[8][4];
  #pragma unroll
  for (int i = 0; i < 8; ++i)
    #pragma unroll
    for (int j = 0; j < 4; ++j)
      acc[i][j] = f32x4{0.f, 0.f, 0.f, 0.f};

  for (int k0 = 0; k0 < K; k0 += 64) {
    // stage A 256x64 (2048 chunks, 8 rounds) + B 128x64 (1024 chunks, 4 rounds)
    #pragma unroll
    for (int i = 0; i < 8; ++i) {
      const int Cc = i * 256 + t;          // 16B chunk id
      const int row = Cc >> 3;
      const int kc = (Cc & 7) ^ (row & 7);
      async16(&Al[(i * 256 + (t & 192)) * 8], &A[(size_t)(bm + row) * K + k0 + kc * 8]);
    }
    #pragma unroll
    for (int i = 0; i < 4; ++i) {
      const int Cc = i * 256 + t;
      const int row = Cc >> 3;
      const int kc = (Cc & 7) ^ (row & 7);
      async16(&Bl[(i * 256 + (t & 192)) * 8], &Bt[(size_t)(bn + row) * K + k0 + kc * 8]);
    }
    __syncthreads();
    #pragma unroll
    for (int kk = 0; kk < 2; ++kk) {
      s16x8 af[8], bfr[4];
      #pragma unroll
      for (int mi = 0; mi < 8; ++mi) {
        const int row = wm * 128 + mi * 16 + lr;
        const int ch = (kk * 4 + lg) ^ (row & 7);
        af[mi] = *(const s16x8*)&Al[row * 64 + ch * 8];
      }
      #pragma unroll
      for (int ni = 0; ni < 4; ++ni) {
        const int row = wn * 64 + ni * 16 + lr;
        const int ch = (kk * 4 + lg) ^ (row & 7);
        bfr[ni] = *(const s16x8*)&Bl[row * 64 + ch * 8];
      }
      __builtin_amdgcn_s_setprio(1);
      #pragma unroll
      for (int mi = 0; mi < 8; ++mi)
        #pragma unroll
        for (int ni = 0; ni < 4; ++ni)
          acc[mi][ni] = __builtin_amdgcn_mfma_f32_16x16x32_bf16(af[mi], bfr[ni], acc[mi][ni], 0, 0, 0);
      __builtin_amdgcn_s_setprio(0);
    }
    __syncthreads();
  }

  // epilogue; C/D layout: col = lane&15, row = (lane>>4)*4 + reg  [m89-verified]
  #pragma unroll
  for (int mi = 0; mi < 8; ++mi) {
    #pragma unroll
    for (int ni = 0; ni < 4; ++ni) {
      const int col = bn + wn * 64 + ni * 16 + lr;
      const float bv = bias[col];
      #pragma unroll
      for (int r = 0; r < 4; ++r) {
        const int row = bm + wm * 128 + mi * 16 + lg * 4 + r;
        const float v = acc[mi][ni][r] + bv;
        if (MODE == 1) {
          OutF[(size_t)row * N + col] = v;
        } else {
          const int which = col >> 11;         // 0=q 1=k 2=v (uniform per block: 2048%128==0)
          const int cc = col & 2047;
          const int h = cc >> 7, d = cc & 127;
          const int b = row >> 11, tp = row & 2047;
          unsigned short* dst = (which == 0) ? Qd : (which == 1 ? Kd : Vd);
          dst[(((size_t)(b * NH + h)) * NT + tp) * HD + d] = f2bf(v);
        }
      }
    }
  }
}

// ---------------- flash attention: 4 waves x 32 q-rows (2 frags), KV tile 64, dbuf ----------------
// Each lane owns TWO q-rows; K-frag LDS reads, V tr-reads, and KV staging SHARED
// across both fragments. Block = 128 q-rows; grid (bh 64, pair 8); pair balance
// (i, 15-i) -> 34 kv-iters const; same-head blocks on one XCD.
// swapped S^T = mfma(K, Q); T13 defer-max; cvt_pk P-pack; packed 8B output stores.
// Final tile skipped by waves 0,1 (fully causal-masked there — exact-zero contribution).
__global__ __launch_bounds__(256, 2)
void k_attn(const unsigned short* __restrict__ Q,
            const unsigned short* __restrict__ Kg,
            const unsigned short* __restrict__ Vg,
            unsigned short* __restrict__ Yatt)   // att [BT][NC] bf16
{
  __shared__ __align__(16) unsigned short Kl[2][64 * 128];  // [key][d], 16B-chunk-swizzled
  __shared__ __align__(16) unsigned short Vl[2][64 * 128];  // subtiled [key/4][d/16][4][16]
  const int bh = blockIdx.x;          // 0..63
  const int pair = blockIdx.y;        // 0..7
  const int b = bh >> 4, h = bh & 15;
  const int t = threadIdx.x, l = t & 63, wv = t >> 6;
  const int lr = l & 15, lg = l >> 4;
  const size_t hoff = (size_t)bh * NT * HD;
  const unsigned short* Qh = Q + hoff;
  const unsigned short* Kh = Kg + hoff;
  const unsigned short* Vh = Vg + hoff;
  const uint32_t vbase0 = lds_off(&Vl[0][0]);

  auto stageKV = [&](int buf, int kv0) {
    #pragma unroll
    for (int i = 0; i < 4; ++i) {
      const int Cc = i * 256 + t;
      {  // K tile: row-major [64][128], 16B chunks swizzled with (row&7)
        const int krow = Cc >> 4;
        const int kc = (Cc & 15) ^ (krow & 7);
        async16(&Kl[buf][(i * 256 + (t & 192)) * 8], &Kh[(size_t)(kv0 + krow) * HD + kc * 8]);
      }
      {  // V tile: subtile S = kq*8+dq holds [4 keys][16 d] row-major
        const int S = Cc >> 3, c8 = Cc & 7;
        const int kq = S >> 3, dq = S & 7;
        const int vk = kq * 4 + (c8 >> 1), vd = dq * 16 + (c8 & 1) * 8;
        async16(&Vl[buf][(i * 256 + (t & 192)) * 8], &Vh[(size_t)(kv0 + vk) * HD + vd]);
      }
    }
  };

  #pragma unroll 1
  for (int rep = 0; rep < 2; ++rep) {
    const int qb16 = rep ? (15 - pair) : pair;   // q-tile of 128 rows
    const int q0w = qb16 * 128 + wv * 32;        // wave's 32-row strip
    const int qrowA = q0w + lr, qrowB = q0w + 16 + lr;

    __syncthreads();  // protect LDS reuse across reps

    s16x8 qfA[4], qfB[4];
    #pragma unroll
    for (int m = 0; m < 4; ++m) {
      qfA[m] = *(const s16x8*)(Qh + (size_t)qrowA * HD + m * 32 + lg * 8);
      qfB[m] = *(const s16x8*)(Qh + (size_t)qrowB * HD + m * 32 + lg * 8);
    }

    f32x4 ytA[8], ytB[8];
    #pragma unroll
    for (int n = 0; n < 8; ++n) { ytA[n] = f32x4{0.f,0.f,0.f,0.f}; ytB[n] = f32x4{0.f,0.f,0.f,0.f}; }
    float mrunA = -1e30f, lrunA = 0.f, mrunB = -1e30f, lrunB = 0.f;

    auto computeTile = [&](int buf, int kv0) {
      // S^T tiles for both q-frags; K frags shared
      f32x4 stA[4], stB[4];
      __builtin_amdgcn_s_setprio(1);
      #pragma unroll
      for (int kt = 0; kt < 4; ++kt) {
        f32x4 a = f32x4{0.f,0.f,0.f,0.f}, bq = f32x4{0.f,0.f,0.f,0.f};
        const int krow = kt * 16 + lr;
        #pragma unroll
        for (int m = 0; m < 4; ++m) {
          const int ch = (m * 4 + lg) ^ (krow & 7);
          s16x8 kf = *(const s16x8*)&Kl[buf][krow * 128 + ch * 8];
          a  = __builtin_amdgcn_mfma_f32_16x16x32_bf16(kf, qfA[m], a, 0, 0, 0);
          bq = __builtin_amdgcn_mfma_f32_16x16x32_bf16(kf, qfB[m], bq, 0, 0, 0);
        }
        stA[kt] = a; stB[kt] = bq;
      }
      __builtin_amdgcn_s_setprio(0);

      // causal mask near diagonal (per frag)
      if (kv0 + 63 > q0w) {
        #pragma unroll
        for (int kt = 0; kt < 4; ++kt)
          #pragma unroll
          for (int r = 0; r < 4; ++r) {
            const int key = kv0 + kt * 16 + lg * 4 + r;
            if (key > qrowA) stA[kt][r] = -3.0e38f;
            if (key > qrowB) stB[kt][r] = -3.0e38f;
          }
      }

      // online softmax x2 (T13 defer-max)
      float tmA = -3.0e38f, tmB = -3.0e38f;
      #pragma unroll
      for (int kt = 0; kt < 4; ++kt)
        #pragma unroll
        for (int r = 0; r < 4; ++r) { tmA = fmaxf(tmA, stA[kt][r]); tmB = fmaxf(tmB, stB[kt][r]); }
      tmA = fmaxf(tmA, __shfl_xor(tmA, 16)); tmA = fmaxf(tmA, __shfl_xor(tmA, 32));
      tmB = fmaxf(tmB, __shfl_xor(tmB, 16)); tmB = fmaxf(tmB, __shfl_xor(tmB, 32));
      if (!__all((tmA - mrunA <= 8.0f) && (tmB - mrunB <= 8.0f))) {
        const float mnA = fmaxf(mrunA, tmA), mnB = fmaxf(mrunB, tmB);
        const float fsA = exp2f(mrunA - mnA), fsB = exp2f(mrunB - mnB);
        mrunA = mnA; mrunB = mnB;
        lrunA *= fsA; lrunB *= fsB;
        #pragma unroll
        for (int n = 0; n < 8; ++n)
          #pragma unroll
          for (int r = 0; r < 4; ++r) { ytA[n][r] *= fsA; ytB[n][r] *= fsB; }
      }

      float pvA[16], pvB[16];
      float psA = 0.f, psB = 0.f;
      #pragma unroll
      for (int kt = 0; kt < 4; ++kt)
        #pragma unroll
        for (int r = 0; r < 4; ++r) {
          const float pa = exp2f(stA[kt][r] - mrunA);
          const float pb = exp2f(stB[kt][r] - mrunB);
          psA += pa; psB += pb;
          pvA[kt * 4 + r] = pa; pvB[kt * 4 + r] = pb;
        }
      lrunA += psA; lrunB += psB;

      // pack P^T frags via v_cvt_pk_bf16_f32
      union { uint32_t w[4]; s16x8 v; } puA[2], puB[2];
      #pragma unroll
      for (int gk = 0; gk < 2; ++gk)
        #pragma unroll
        for (int w = 0; w < 4; ++w) {
          const int i0 = (gk * 2 + (w >> 1)) * 4 + (w & 1) * 2;
          asm("v_cvt_pk_bf16_f32 %0, %1, %2" : "=v"(puA[gk].w[w]) : "v"(pvA[i0]), "v"(pvA[i0 + 1]));
          asm("v_cvt_pk_bf16_f32 %0, %1, %2" : "=v"(puB[gk].w[w]) : "v"(pvB[i0]), "v"(pvB[i0 + 1]));
        }

      // PV: V^T frags shared across both q-frags
      const uint32_t vb = vbase0 + (uint32_t)buf * 16384;
      #pragma unroll
      for (int gk = 0; gk < 2; ++gk) {
        s16x4 va[8], vb2[8];
        #pragma unroll
        for (int n = 0; n < 8; ++n) {
          const uint32_t a0 = vb + ((uint32_t)((gk * 8 + lg) * 8 + n)) * 128 + (uint32_t)lr * 8;
          asm volatile("ds_read_b64_tr_b16 %0, %1" : "=v"(va[n])  : "v"(a0));
          asm volatile("ds_read_b64_tr_b16 %0, %1" : "=v"(vb2[n]) : "v"(a0 + 4096));
        }
        asm volatile("s_waitcnt lgkmcnt(0)" ::: "memory");
        __builtin_amdgcn_sched_barrier(0);
        __builtin_amdgcn_s_setprio(1);
        #pragma unroll
        for (int n = 0; n < 8; ++n) {
          s16x8 vf;
          vf[0] = va[n][0];  vf[1] = va[n][1];  vf[2] = va[n][2];  vf[3] = va[n][3];
          vf[4] = vb2[n][0]; vf[5] = vb2[n][1]; vf[6] = vb2[n][2]; vf[7] = vb2[n][3];
          ytA[n] = __builtin_amdgcn_mfma_f32_16x16x32_bf16(vf, puA[gk].v, ytA[n], 0, 0, 0);
          ytB[n] = __builtin_amdgcn_mfma_f32_16x16x32_bf16(vf, puB[gk].v, ytB[n], 0, 0, 0);
        }
        __builtin_amdgcn_s_setprio(0);
      }
    };

    const int nkv = 2 * qb16 + 2;
    stageKV(0, 0);
    asm volatile("s_waitcnt vmcnt(0)" ::: "memory");
    __syncthreads();
    int buf = 0;
    #pragma unroll 1
    for (int kv = 0; kv < nkv - 1; ++kv) {
      stageKV(buf ^ 1, (kv + 1) * 64);      // issue next tile's loads first
      computeTile(buf, kv * 64);            // overlap compute with loads
      asm volatile("s_waitcnt vmcnt(0)" ::: "memory");
      __builtin_amdgcn_s_barrier();
      buf ^= 1;
    }
    if ((nkv - 1) * 64 <= q0w + 31)         // waves 0,1: final tile fully masked -> skip
      computeTile(buf, (nkv - 1) * 64);

    // finalize both frags: reduce l, scale, packed 8B stores
    lrunA += __shfl_xor(lrunA, 16); lrunA += __shfl_xor(lrunA, 32);
    lrunB += __shfl_xor(lrunB, 16); lrunB += __shfl_xor(lrunB, 32);
    const float invA = 1.f / lrunA, invB = 1.f / lrunB;
    unsigned short* yrowA = Yatt + (size_t)(b * NT + qrowA) * NC + h * HD;
    unsigned short* yrowB = Yatt + (size_t)(b * NT + qrowB) * NC + h * HD;
    #pragma unroll
    for (int n = 0; n < 8; ++n) {
      uint32_t u0, u1;
      asm("v_cvt_pk_bf16_f32 %0, %1, %2" : "=v"(u0) : "v"(ytA[n][0] * invA), "v"(ytA[n][1] * invA));
      asm("v_cvt_pk_bf16_f32 %0, %1, %2" : "=v"(u1) : "v"(ytA[n][2] * invA), "v"(ytA[n][3] * invA));
      uint2 pk; pk.x = u0; pk.y = u1;
      *(uint2*)(yrowA + n * 16 + lg * 4) = pk;
      asm("v_cvt_pk_bf16_f32 %0, %1, %2" : "=v"(u0) : "v"(ytB[n][0] * invB), "v"(ytB[n][1] * invB));
      asm("v_cvt_pk_bf16_f32 %0, %1, %2" : "=v"(u1) : "v"(ytB[n][2] * invB), "v"(ytB[n][3] * invB));
      pk.x = u0; pk.y = u1;
      *(uint2*)(yrowB + n * 16 + lg * 4) = pk;
    }
  }
}

extern "C" void kernel_launch(void* const* d_in, const int* in_sizes, int n_in,
                              void* d_out, int out_size, void* d_ws, size_t ws_size,
                              hipStream_t stream) {
  (void)in_sizes; (void)n_in; (void)out_size; (void)ws_size;
  const float* x     = (const float*)d_in[0];
  const float* Wqkv  = (const float*)d_in[1];
  const float* bqkv  = (const float*)d_in[2];
  const float* Wproj = (const float*)d_in[3];
  const float* bproj = (const float*)d_in[4];
  float* out = (float*)d_out;
  char* ws = (char*)d_ws;

  // workspace layout (160 MB total)
  unsigned short* xb     = (unsigned short*)(ws);               // 32MB  [BT][NC] bf16
  unsigned short* WqkvT  = (unsigned short*)(ws + 33554432);    // 24MB  [6144][2048]
  unsigned short* WprojT = (unsigned short*)(ws + 58720256);    // 8MB   [2048][2048]
  unsigned short* Qb     = (unsigned short*)(ws + 67108864);    // 32MB  [BH][T][D]
  unsigned short* Kb     = (unsigned short*)(ws + 100663296);   // 32MB
  unsigned short* Vb     = (unsigned short*)(ws + 134217728);   // 32MB
  unsigned short* att    = xb;  // reuse (xb dead after GEMM1)

  k_convert_bf16<<<dim3(8192), dim3(256), 0, stream>>>(x, xb, BT * NC / 8);
  k_transpose_bf16<<<dim3(96, 32), dim3(256), 0, stream>>>(Wqkv, WqkvT, NC, 3 * NC);
  k_transpose_bf16<<<dim3(32, 32), dim3(256), 0, stream>>>(Wproj, WprojT, NC, NC);
  k_gemm_bt2<0><<<dim3(48, 32), dim3(256), 0, stream>>>(xb, WqkvT, bqkv, nullptr, Qb, Kb, Vb, BT, 3 * NC, NC);
  k_rope<<<dim3(4096), dim3(256), 0, stream>>>(Qb, Kb);
  k_attn<<<dim3(64, 8), dim3(256), 0, stream>>>(Qb, Kb, Vb, att);
  k_gemm_bt2<1><<<dim3(16, 32), dim3(256), 0, stream>>>(att, WprojT, bproj, out, nullptr, nullptr, nullptr, BT, NC, NC);
}

// Round 14
// 398.534 us; speedup vs baseline: 1.1389x; 1.0252x over previous
//
#include <hip/hip_runtime.h>
#include <hip/hip_bf16.h>
#include <stdint.h>
#include <math.h>

// Problem constants
#define NB 4
#define NT 2048
#define NC 2048
#define NH 16
#define HD 128
#define BT (NB*NT)   // 8192

typedef __attribute__((ext_vector_type(8))) short s16x8;
typedef __attribute__((ext_vector_type(4))) short s16x4;
typedef __attribute__((ext_vector_type(4))) float f32x4;

typedef __attribute__((address_space(1))) void as1_void;
typedef __attribute__((address_space(3))) void as3_void;

static __device__ __forceinline__ unsigned short f2bf(float f) {
  union { float f; uint32_t u; } v; v.f = f;
  return (unsigned short)((v.u + 0x7fffu + ((v.u >> 16) & 1u)) >> 16);
}
static __device__ __forceinline__ float bf2f(unsigned short u) {
  union { uint32_t u; float f; } v; v.u = ((uint32_t)u) << 16;
  return v.f;
}
static __device__ __forceinline__ void async16(unsigned short* lds, const unsigned short* g) {
  __builtin_amdgcn_global_load_lds((as1_void*)g, (as3_void*)lds, 16, 0, 0);
}
static __device__ __forceinline__ uint32_t lds_off(void* p) {
  return (uint32_t)(size_t)(as3_void*)p;
}

// ---------------- fp32 -> bf16 convert (vectorized, 8 elems/thread) ----------------
__global__ void k_convert_bf16(const float* __restrict__ in, unsigned short* __restrict__ out, int n8) {
  int i = blockIdx.x * blockDim.x + threadIdx.x;
  if (i >= n8) return;
  const float4* p = (const float4*)in + (size_t)i * 2;
  float4 a = p[0], b = p[1];
  union { unsigned short s[8]; uint4 u; } o;
  o.s[0] = f2bf(a.x); o.s[1] = f2bf(a.y); o.s[2] = f2bf(a.z); o.s[3] = f2bf(a.w);
  o.s[4] = f2bf(b.x); o.s[5] = f2bf(b.y); o.s[6] = f2bf(b.z); o.s[7] = f2bf(b.w);
  ((uint4*)out)[i] = o.u;
}

// ---------------- transpose + convert: W [K][N] fp32 -> WT [N][K] bf16 ----------------
__global__ void k_transpose_bf16(const float* __restrict__ W, unsigned short* __restrict__ WT, int K, int N) {
  __shared__ unsigned short tile[64][65];
  const int k0 = blockIdx.y * 64, n0 = blockIdx.x * 64;
  const int t = threadIdx.x;
  const int jj = t & 63, base_i = t >> 6;
  #pragma unroll
  for (int p = 0; p < 16; ++p) {
    int i = p * 4 + base_i;
    tile[i][jj] = f2bf(W[(size_t)(k0 + i) * N + n0 + jj]);
  }
  __syncthreads();
  #pragma unroll
  for (int p = 0; p < 16; ++p) {
    int j = p * 4 + base_i;
    WT[(size_t)(n0 + j) * K + k0 + jj] = tile[jj][j];
  }
}

// ---------------- GEMM 256x128 block, BK=64, 256 thr / 4 waves (2Mx2N) ----------------
// FROZEN core (session GEMM optimum): wave tile 128x64, LDS 48 KiB, 2 blocks/CU,
// 2-phase __syncthreads, chunk-XOR swizzle (0 conflicts), natural blockIdx.
// __launch_bounds__(256,2) MANDATORY (r3/r8 spills). Structural ledger: r5 4-phase,
// r6 256², r12 ring-3 all regressed — do not re-attempt without the full m201 template.
// MODE 0: scatter bf16 Q/K/V [B][H][T][D] with FUSED RoPE for Q/K — a block's
// 128-col panel covers one head's full d-range; the rope pair (d, d+64) lives in
// the partner wave (wn^1), same lane & (mi,ni,r). 2-barrier LDS exchange per
// 2-mi chunk through the dead Al buffer ([elem][wv][lane] layout, conflict-free,
// exactly 8192 floats). Q additionally scaled by (1/sqrt(128))*log2e.
// MODE 1: fp32 row-major out.
template<int MODE>
__global__ __launch_bounds__(256, 2)
void k_gemm_bt2(const unsigned short* __restrict__ A,
                const unsigned short* __restrict__ Bt,
                const float* __restrict__ bias,
                float* __restrict__ OutF,
                unsigned short* __restrict__ Qd,
                unsigned short* __restrict__ Kd,
                unsigned short* __restrict__ Vd,
                int M, int N, int K)
{
  __shared__ __align__(16) unsigned short Al[256 * 64];
  __shared__ __align__(16) unsigned short Bl[128 * 64];
  const int t = threadIdx.x;
  const int l = t & 63;
  const int wv = t >> 6;
  const int wm = wv >> 1, wn = wv & 1;     // 2 x 2 wave grid; wave tile 128x64
  const int bm = blockIdx.y * 256, bn = blockIdx.x * 128;
  const int lr = l & 15, lg = l >> 4;

  f32x4 acc[8][4];
  #pragma unroll
  for (int i = 0; i < 8; ++i)
    #pragma unroll
    for (int j = 0; j < 4; ++j)
      acc[i][j] = f32x4{0.f, 0.f, 0.f, 0.f};

  for (int k0 = 0; k0 < K; k0 += 64) {
    // stage A 256x64 (2048 chunks, 8 rounds) + B 128x64 (1024 chunks, 4 rounds)
    #pragma unroll
    for (int i = 0; i < 8; ++i) {
      const int Cc = i * 256 + t;          // 16B chunk id
      const int row = Cc >> 3;
      const int kc = (Cc & 7) ^ (row & 7);
      async16(&Al[(i * 256 + (t & 192)) * 8], &A[(size_t)(bm + row) * K + k0 + kc * 8]);
    }
    #pragma unroll
    for (int i = 0; i < 4; ++i) {
      const int Cc = i * 256 + t;
      const int row = Cc >> 3;
      const int kc = (Cc & 7) ^ (row & 7);
      async16(&Bl[(i * 256 + (t & 192)) * 8], &Bt[(size_t)(bn + row) * K + k0 + kc * 8]);
    }
    __syncthreads();
    #pragma unroll
    for (int kk = 0; kk < 2; ++kk) {
      s16x8 af[8], bfr[4];
      #pragma unroll
      for (int mi = 0; mi < 8; ++mi) {
        const int row = wm * 128 + mi * 16 + lr;
        const int ch = (kk * 4 + lg) ^ (row & 7);
        af[mi] = *(const s16x8*)&Al[row * 64 + ch * 8];
      }
      #pragma unroll
      for (int ni = 0; ni < 4; ++ni) {
        const int row = wn * 64 + ni * 16 + lr;
        const int ch = (kk * 4 + lg) ^ (row & 7);
        bfr[ni] = *(const s16x8*)&Bl[row * 64 + ch * 8];
      }
      __builtin_amdgcn_s_setprio(1);
      #pragma unroll
      for (int mi = 0; mi < 8; ++mi)
        #pragma unroll
        for (int ni = 0; ni < 4; ++ni)
          acc[mi][ni] = __builtin_amdgcn_mfma_f32_16x16x32_bf16(af[mi], bfr[ni], acc[mi][ni], 0, 0, 0);
      __builtin_amdgcn_s_setprio(0);
    }
    __syncthreads();
  }

  // epilogue; C/D layout: col = lane&15, row = (lane>>4)*4 + reg  [m89-verified]
  if (MODE == 1) {
    #pragma unroll
    for (int mi = 0; mi < 8; ++mi) {
      #pragma unroll
      for (int ni = 0; ni < 4; ++ni) {
        const int col = bn + wn * 64 + ni * 16 + lr;
        const float bv = bias[col];
        #pragma unroll
        for (int r = 0; r < 4; ++r) {
          const int row = bm + wm * 128 + mi * 16 + lg * 4 + r;
          OutF[(size_t)row * N + col] = acc[mi][ni][r] + bv;
        }
      }
    }
  } else {
    const int whichB = bn >> 11;            // 0=q 1=k 2=v (block-uniform: panel 128-aligned)
    const int bb = bm >> 11;                // batch (block-uniform: 2048%256==0)
    const int h = (bn & 2047) >> 7;         // head (block-uniform)
    unsigned short* dst = (whichB == 0) ? Qd : (whichB == 1 ? Kd : Vd);
    if (whichB == 2) {
      // V: plain scatter
      #pragma unroll
      for (int mi = 0; mi < 8; ++mi) {
        #pragma unroll
        for (int ni = 0; ni < 4; ++ni) {
          const int col = bn + wn * 64 + ni * 16 + lr;
          const float bv = bias[col];
          const int d = wn * 64 + ni * 16 + lr;
          #pragma unroll
          for (int r = 0; r < 4; ++r) {
            const int tp = (bm + wm * 128 + mi * 16 + lg * 4 + r) & 2047;
            dst[(((size_t)(bb * NH + h)) * NT + tp) * HD + d] = f2bf(acc[mi][ni][r] + bv);
          }
        }
      }
    } else {
      // Q/K: fused RoPE. own pairs with partner wave wn^1 (same lane, same regs).
      const float qsc = (whichB == 0) ? (0.08838834764831845f * 1.4426950408889634f) : 1.0f;
      float invf[4];
      #pragma unroll
      for (int ni = 0; ni < 4; ++ni)
        invf[ni] = exp2f(-(float)(ni * 16 + lr) * 0.2076205059304602f);  // log2(10000)/64
      float* Ex = (float*)Al;               // 8192 floats, dead after K-loop
      #pragma unroll
      for (int mc = 0; mc < 4; ++mc) {      // mi chunk {2mc, 2mc+1}
        __syncthreads();
        #pragma unroll
        for (int dm = 0; dm < 2; ++dm)
          #pragma unroll
          for (int ni = 0; ni < 4; ++ni) {
            const float bv = bias[bn + wn * 64 + ni * 16 + lr];
            #pragma unroll
            for (int r = 0; r < 4; ++r)
              Ex[(dm * 16 + ni * 4 + r) * 256 + wv * 64 + l] = acc[mc * 2 + dm][ni][r] + bv;
          }
        __syncthreads();
        #pragma unroll
        for (int dm = 0; dm < 2; ++dm)
          #pragma unroll
          for (int ni = 0; ni < 4; ++ni) {
            const float bv = bias[bn + wn * 64 + ni * 16 + lr];
            const int d = wn * 64 + ni * 16 + lr;
            #pragma unroll
            for (int r = 0; r < 4; ++r) {
              const int mi = mc * 2 + dm;
              const int tp = (bm + wm * 128 + mi * 16 + lg * 4 + r) & 2047;
              const float own = acc[mi][ni][r] + bv;
              const float oth = Ex[(dm * 16 + ni * 4 + r) * 256 + (wv ^ 1) * 64 + l];
              float s, c;
              __sincosf((float)tp * invf[ni], &s, &c);
              const float out = ((wn == 0) ? (own * c - oth * s) : (own * c + oth * s)) * qsc;
              dst[(((size_t)(bb * NH + h)) * NT + tp) * HD + d] = f2bf(out);
            }
          }
      }
    }
  }
}

// ---------------- flash attention: 4 waves x 32 q-rows (2 frags), KV tile 64, dbuf ----------------
// Each lane owns TWO q-rows; K-frag LDS reads, V tr-reads, and KV staging SHARED
// across both fragments. Block = 128 q-rows; grid (bh 64, pair 8); pair balance
// (i, 15-i) -> 34 kv-iters const; same-head blocks on one XCD.
// swapped S^T = mfma(K, Q); T13 defer-max; cvt_pk P-pack; packed 8B output stores.
// Final tile skipped by waves 0,1 (fully causal-masked there — exact-zero contribution).
__global__ __launch_bounds__(256, 2)
void k_attn(const unsigned short* __restrict__ Q,
            const unsigned short* __restrict__ Kg,
            const unsigned short* __restrict__ Vg,
            unsigned short* __restrict__ Yatt)   // att [BT][NC] bf16
{
  __shared__ __align__(16) unsigned short Kl[2][64 * 128];  // [key][d], 16B-chunk-swizzled
  __shared__ __align__(16) unsigned short Vl[2][64 * 128];  // subtiled [key/4][d/16][4][16]
  const int bh = blockIdx.x;          // 0..63
  const int pair = blockIdx.y;        // 0..7
  const int b = bh >> 4, h = bh & 15;
  const int t = threadIdx.x, l = t & 63, wv = t >> 6;
  const int lr = l & 15, lg = l >> 4;
  const size_t hoff = (size_t)bh * NT * HD;
  const unsigned short* Qh = Q + hoff;
  const unsigned short* Kh = Kg + hoff;
  const unsigned short* Vh = Vg + hoff;
  const uint32_t vbase0 = lds_off(&Vl[0][0]);

  auto stageKV = [&](int buf, int kv0) {
    #pragma unroll
    for (int i = 0; i < 4; ++i) {
      const int Cc = i * 256 + t;
      {  // K tile: row-major [64][128], 16B chunks swizzled with (row&7)
        const int krow = Cc >> 4;
        const int kc = (Cc & 15) ^ (krow & 7);
        async16(&Kl[buf][(i * 256 + (t & 192)) * 8], &Kh[(size_t)(kv0 + krow) * HD + kc * 8]);
      }
      {  // V tile: subtile S = kq*8+dq holds [4 keys][16 d] row-major
        const int S = Cc >> 3, c8 = Cc & 7;
        const int kq = S >> 3, dq = S & 7;
        const int vk = kq * 4 + (c8 >> 1), vd = dq * 16 + (c8 & 1) * 8;
        async16(&Vl[buf][(i * 256 + (t & 192)) * 8], &Vh[(size_t)(kv0 + vk) * HD + vd]);
      }
    }
  };

  #pragma unroll 1
  for (int rep = 0; rep < 2; ++rep) {
    const int qb16 = rep ? (15 - pair) : pair;   // q-tile of 128 rows
    const int q0w = qb16 * 128 + wv * 32;        // wave's 32-row strip
    const int qrowA = q0w + lr, qrowB = q0w + 16 + lr;

    __syncthreads();  // protect LDS reuse across reps

    s16x8 qfA[4], qfB[4];
    #pragma unroll
    for (int m = 0; m < 4; ++m) {
      qfA[m] = *(const s16x8*)(Qh + (size_t)qrowA * HD + m * 32 + lg * 8);
      qfB[m] = *(const s16x8*)(Qh + (size_t)qrowB * HD + m * 32 + lg * 8);
    }

    f32x4 ytA[8], ytB[8];
    #pragma unroll
    for (int n = 0; n < 8; ++n) { ytA[n] = f32x4{0.f,0.f,0.f,0.f}; ytB[n] = f32x4{0.f,0.f,0.f,0.f}; }
    float mrunA = -1e30f, lrunA = 0.f, mrunB = -1e30f, lrunB = 0.f;

    auto computeTile = [&](int buf, int kv0) {
      // S^T tiles for both q-frags; K frags shared
      f32x4 stA[4], stB[4];
      __builtin_amdgcn_s_setprio(1);
      #pragma unroll
      for (int kt = 0; kt < 4; ++kt) {
        f32x4 a = f32x4{0.f,0.f,0.f,0.f}, bq = f32x4{0.f,0.f,0.f,0.f};
        const int krow = kt * 16 + lr;
        #pragma unroll
        for (int m = 0; m < 4; ++m) {
          const int ch = (m * 4 + lg) ^ (krow & 7);
          s16x8 kf = *(const s16x8*)&Kl[buf][krow * 128 + ch * 8];
          a  = __builtin_amdgcn_mfma_f32_16x16x32_bf16(kf, qfA[m], a, 0, 0, 0);
          bq = __builtin_amdgcn_mfma_f32_16x16x32_bf16(kf, qfB[m], bq, 0, 0, 0);
        }
        stA[kt] = a; stB[kt] = bq;
      }
      __builtin_amdgcn_s_setprio(0);

      // causal mask near diagonal (per frag)
      if (kv0 + 63 > q0w) {
        #pragma unroll
        for (int kt = 0; kt < 4; ++kt)
          #pragma unroll
          for (int r = 0; r < 4; ++r) {
            const int key = kv0 + kt * 16 + lg * 4 + r;
            if (key > qrowA) stA[kt][r] = -3.0e38f;
            if (key > qrowB) stB[kt][r] = -3.0e38f;
          }
      }

      // online softmax x2 (T13 defer-max)
      float tmA = -3.0e38f, tmB = -3.0e38f;
      #pragma unroll
      for (int kt = 0; kt < 4; ++kt)
        #pragma unroll
        for (int r = 0; r < 4; ++r) { tmA = fmaxf(tmA, stA[kt][r]); tmB = fmaxf(tmB, stB[kt][r]); }
      tmA = fmaxf(tmA, __shfl_xor(tmA, 16)); tmA = fmaxf(tmA, __shfl_xor(tmA, 32));
      tmB = fmaxf(tmB, __shfl_xor(tmB, 16)); tmB = fmaxf(tmB, __shfl_xor(tmB, 32));
      if (!__all((tmA - mrunA <= 8.0f) && (tmB - mrunB <= 8.0f))) {
        const float mnA = fmaxf(mrunA, tmA), mnB = fmaxf(mrunB, tmB);
        const float fsA = exp2f(mrunA - mnA), fsB = exp2f(mrunB - mnB);
        mrunA = mnA; mrunB = mnB;
        lrunA *= fsA; lrunB *= fsB;
        #pragma unroll
        for (int n = 0; n < 8; ++n)
          #pragma unroll
          for (int r = 0; r < 4; ++r) { ytA[n][r] *= fsA; ytB[n][r] *= fsB; }
      }

      float pvA[16], pvB[16];
      float psA = 0.f, psB = 0.f;
      #pragma unroll
      for (int kt = 0; kt < 4; ++kt)
        #pragma unroll
        for (int r = 0; r < 4; ++r) {
          const float pa = exp2f(stA[kt][r] - mrunA);
          const float pb = exp2f(stB[kt][r] - mrunB);
          psA += pa; psB += pb;
          pvA[kt * 4 + r] = pa; pvB[kt * 4 + r] = pb;
        }
      lrunA += psA; lrunB += psB;

      // pack P^T frags via v_cvt_pk_bf16_f32
      union { uint32_t w[4]; s16x8 v; } puA[2], puB[2];
      #pragma unroll
      for (int gk = 0; gk < 2; ++gk)
        #pragma unroll
        for (int w = 0; w < 4; ++w) {
          const int i0 = (gk * 2 + (w >> 1)) * 4 + (w & 1) * 2;
          asm("v_cvt_pk_bf16_f32 %0, %1, %2" : "=v"(puA[gk].w[w]) : "v"(pvA[i0]), "v"(pvA[i0 + 1]));
          asm("v_cvt_pk_bf16_f32 %0, %1, %2" : "=v"(puB[gk].w[w]) : "v"(pvB[i0]), "v"(pvB[i0 + 1]));
        }

      // PV: V^T frags shared across both q-frags
      const uint32_t vb = vbase0 + (uint32_t)buf * 16384;
      #pragma unroll
      for (int gk = 0; gk < 2; ++gk) {
        s16x4 va[8], vb2[8];
        #pragma unroll
        for (int n = 0; n < 8; ++n) {
          const uint32_t a0 = vb + ((uint32_t)((gk * 8 + lg) * 8 + n)) * 128 + (uint32_t)lr * 8;
          asm volatile("ds_read_b64_tr_b16 %0, %1" : "=v"(va[n])  : "v"(a0));
          asm volatile("ds_read_b64_tr_b16 %0, %1" : "=v"(vb2[n]) : "v"(a0 + 4096));
        }
        asm volatile("s_waitcnt lgkmcnt(0)" ::: "memory");
        __builtin_amdgcn_sched_barrier(0);
        __builtin_amdgcn_s_setprio(1);
        #pragma unroll
        for (int n = 0; n < 8; ++n) {
          s16x8 vf;
          vf[0] = va[n][0];  vf[1] = va[n][1];  vf[2] = va[n][2];  vf[3] = va[n][3];
          vf[4] = vb2[n][0]; vf[5] = vb2[n][1]; vf[6] = vb2[n][2]; vf[7] = vb2[n][3];
          ytA[n] = __builtin_amdgcn_mfma_f32_16x16x32_bf16(vf, puA[gk].v, ytA[n], 0, 0, 0);
          ytB[n] = __builtin_amdgcn_mfma_f32_16x16x32_bf16(vf, puB[gk].v, ytB[n], 0, 0, 0);
        }
        __builtin_amdgcn_s_setprio(0);
      }
    };

    const int nkv = 2 * qb16 + 2;
    stageKV(0, 0);
    asm volatile("s_waitcnt vmcnt(0)" ::: "memory");
    __syncthreads();
    int buf = 0;
    #pragma unroll 1
    for (int kv = 0; kv < nkv - 1; ++kv) {
      stageKV(buf ^ 1, (kv + 1) * 64);      // issue next tile's loads first
      computeTile(buf, kv * 64);            // overlap compute with loads
      asm volatile("s_waitcnt vmcnt(0)" ::: "memory");
      __builtin_amdgcn_s_barrier();
      buf ^= 1;
    }
    if ((nkv - 1) * 64 <= q0w + 31)         // waves 0,1: final tile fully masked -> skip
      computeTile(buf, (nkv - 1) * 64);

    // finalize both frags: reduce l, scale, packed 8B stores
    lrunA += __shfl_xor(lrunA, 16); lrunA += __shfl_xor(lrunA, 32);
    lrunB += __shfl_xor(lrunB, 16); lrunB += __shfl_xor(lrunB, 32);
    const float invA = 1.f / lrunA, invB = 1.f / lrunB;
    unsigned short* yrowA = Yatt + (size_t)(b * NT + qrowA) * NC + h * HD;
    unsigned short* yrowB = Yatt + (size_t)(b * NT + qrowB) * NC + h * HD;
    #pragma unroll
    for (int n = 0; n < 8; ++n) {
      uint32_t u0, u1;
      asm("v_cvt_pk_bf16_f32 %0, %1, %2" : "=v"(u0) : "v"(ytA[n][0] * invA), "v"(ytA[n][1] * invA));
      asm("v_cvt_pk_bf16_f32 %0, %1, %2" : "=v"(u1) : "v"(ytA[n][2] * invA), "v"(ytA[n][3] * invA));
      uint2 pk; pk.x = u0; pk.y = u1;
      *(uint2*)(yrowA + n * 16 + lg * 4) = pk;
      asm("v_cvt_pk_bf16_f32 %0, %1, %2" : "=v"(u0) : "v"(ytB[n][0] * invB), "v"(ytB[n][1] * invB));
      asm("v_cvt_pk_bf16_f32 %0, %1, %2" : "=v"(u1) : "v"(ytB[n][2] * invB), "v"(ytB[n][3] * invB));
      pk.x = u0; pk.y = u1;
      *(uint2*)(yrowB + n * 16 + lg * 4) = pk;
    }
  }
}

extern "C" void kernel_launch(void* const* d_in, const int* in_sizes, int n_in,
                              void* d_out, int out_size, void* d_ws, size_t ws_size,
                              hipStream_t stream) {
  (void)in_sizes; (void)n_in; (void)out_size; (void)ws_size;
  const float* x     = (const float*)d_in[0];
  const float* Wqkv  = (const float*)d_in[1];
  const float* bqkv  = (const float*)d_in[2];
  const float* Wproj = (const float*)d_in[3];
  const float* bproj = (const float*)d_in[4];
  float* out = (float*)d_out;
  char* ws = (char*)d_ws;

  // workspace layout (160 MB total)
  unsigned short* xb     = (unsigned short*)(ws);               // 32MB  [BT][NC] bf16
  unsigned short* WqkvT  = (unsigned short*)(ws + 33554432);    // 24MB  [6144][2048]
  unsigned short* WprojT = (unsigned short*)(ws + 58720256);    // 8MB   [2048][2048]
  unsigned short* Qb     = (unsigned short*)(ws + 67108864);    // 32MB  [BH][T][D]
  unsigned short* Kb     = (unsigned short*)(ws + 100663296);   // 32MB
  unsigned short* Vb     = (unsigned short*)(ws + 134217728);   // 32MB
  unsigned short* att    = xb;  // reuse (xb dead after GEMM1)

  k_convert_bf16<<<dim3(8192), dim3(256), 0, stream>>>(x, xb, BT * NC / 8);
  k_transpose_bf16<<<dim3(96, 32), dim3(256), 0, stream>>>(Wqkv, WqkvT, NC, 3 * NC);
  k_transpose_bf16<<<dim3(32, 32), dim3(256), 0, stream>>>(Wproj, WprojT, NC, NC);
  k_gemm_bt2<0><<<dim3(48, 32), dim3(256), 0, stream>>>(xb, WqkvT, bqkv, nullptr, Qb, Kb, Vb, BT, 3 * NC, NC);
  k_attn<<<dim3(64, 8), dim3(256), 0, stream>>>(Qb, Kb, Vb, att);
  k_gemm_bt2<1><<<dim3(16, 32), dim3(256), 0, stream>>>(att, WprojT, bproj, out, nullptr, nullptr, nullptr, BT, NC, NC);
}